// Round 1
// baseline (272.223 us; speedup 1.0000x reference)
//
#include <hip/hip_runtime.h>
#include <stdint.h>

#define B_ 2
#define S_ 2048
#define D_ 1024
#define HD_ 64
#define DKV_ 256

typedef __attribute__((ext_vector_type(8))) __bf16 bf16x8;
typedef __attribute__((ext_vector_type(4))) float f32x4;
typedef __attribute__((ext_vector_type(4))) float float4v;
typedef __attribute__((ext_vector_type(4))) short s16x4;

__device__ __forceinline__ unsigned short f2bf(float f) {
  union { float f; uint32_t u; } v; v.f = f;
  uint32_t r = v.u + 0x7FFFu + ((v.u >> 16) & 1u);
  return (unsigned short)(r >> 16);
}

__device__ __forceinline__ void gload16(const void* g, void* l) {
  __builtin_amdgcn_global_load_lds(
      (const __attribute__((address_space(1))) uint32_t*)g,
      (__attribute__((address_space(3))) uint32_t*)l, 16, 0, 0);
}

__device__ __forceinline__ f32x4 mfma16(bf16x8 a, bf16x8 b, f32x4 c) {
  return __builtin_amdgcn_mfma_f32_16x16x32_bf16(a, b, c, 0, 0, 0);
}

// ---------------- elementwise fp32 -> bf16 ----------------
__global__ void k_cvt(const float* __restrict__ in, unsigned short* __restrict__ out) {
  size_t i = ((size_t)blockIdx.x * 256 + threadIdx.x) * 4;
  float4v f = *(const float4v*)(in + i);
  s16x4 o;
#pragma unroll
  for (int r = 0; r < 4; ++r) o[r] = (short)f2bf(f[r]);
  *(s16x4*)(out + i) = o;
}

// ---------------- W [K][N] fp32 -> Wt [N][K] bf16 ----------------
__global__ void k_tcvt(const float* __restrict__ W, unsigned short* __restrict__ Wt,
                       int K, int N) {
  __shared__ unsigned short t[32][33];
  int n0 = blockIdx.x * 32, k0 = blockIdx.y * 32;
  int tx = threadIdx.x & 31, ty = threadIdx.x >> 5;
#pragma unroll
  for (int i = 0; i < 32; i += 8)
    t[ty + i][tx] = f2bf(W[(size_t)(k0 + ty + i) * N + n0 + tx]);
  __syncthreads();
#pragma unroll
  for (int i = 0; i < 32; i += 8)
    Wt[(size_t)(n0 + ty + i) * K + k0 + tx] = t[tx][ty + i];
}

// ---------------- bf16 transpose per batch: src [R][C] -> dst [C][R] ----------------
__global__ void k_tbf(const unsigned short* __restrict__ src, unsigned short* __restrict__ dst,
                      int R, int C) {
  __shared__ unsigned short t[32][33];
  size_t base = (size_t)blockIdx.z * R * C;
  int c0 = blockIdx.x * 32, r0 = blockIdx.y * 32;
  int tx = threadIdx.x & 31, ty = threadIdx.x >> 5;
#pragma unroll
  for (int i = 0; i < 32; i += 8)
    t[ty + i][tx] = src[base + (size_t)(r0 + ty + i) * C + c0 + tx];
  __syncthreads();
#pragma unroll
  for (int i = 0; i < 32; i += 8)
    dst[base + (size_t)(c0 + ty + i) * R + r0 + tx] = t[tx][ty + i];
}

// ---------------- GEMM: C[M,N] = A[M,K] * Bt[N,K]^T + bias ----------------
// A,Bt bf16 row-major; 128x128 tile, BK=64, 4 waves, double-buffered LDS,
// global_load_lds w/ pre-swizzled source (chunk ^= row&7 within 128B rows).
template <bool OUTF32>
__global__ __launch_bounds__(256, 2) void k_gemm(
    const unsigned short* __restrict__ A, const unsigned short* __restrict__ Bt,
    const float* __restrict__ bias, void* __restrict__ Cout, int M, int N, int K) {
  __shared__ char lds[65536];
  const int lane = threadIdx.x & 63, wid = threadIdx.x >> 6;
  const int r15 = lane & 15, j = lane >> 4;
  const int wm = wid >> 1, wn = wid & 1;
  const size_t strideb = (size_t)K * 2;
  const char* Ab = (const char*)A + (size_t)blockIdx.x * 128 * strideb;
  const char* Bb = (const char*)Bt + (size_t)blockIdx.y * 128 * strideb;
  const int srow = lane >> 3;
  const int scol = ((lane & 7) ^ srow) << 4;

  f32x4 acc[4][4];
#pragma unroll
  for (int a = 0; a < 4; ++a)
#pragma unroll
    for (int b = 0; b < 4; ++b) acc[a][b] = (f32x4){0.f, 0.f, 0.f, 0.f};

  auto stage = [&](int kt, int buf) {
    char* as = lds + buf * 32768;
    char* bs = as + 16384;
    const char* Ag = Ab + kt * 128;
    const char* Bg = Bb + kt * 128;
#pragma unroll
    for (int i = 0; i < 4; ++i) {
      int chunk = i * 4 + wid;
      size_t ro = (size_t)(chunk * 8 + srow) * strideb + scol;
      gload16(Ag + ro, as + chunk * 1024);
      gload16(Bg + ro, bs + chunk * 1024);
    }
  };

  stage(0, 0);
  __syncthreads();
  const int nk = K >> 6;
  const int ca0 = ((0 * 4 + j) ^ (r15 & 7)) << 4;
  const int ca1 = ((1 * 4 + j) ^ (r15 & 7)) << 4;

  for (int kt = 0; kt < nk; ++kt) {
    if (kt + 1 < nk) stage(kt + 1, (kt + 1) & 1);
    const char* as = lds + (kt & 1) * 32768;
    const char* bs = as + 16384;
    bf16x8 af[4][2], bf[4][2];
#pragma unroll
    for (int mi = 0; mi < 4; ++mi) {
      int row = wm * 64 + mi * 16 + r15;
      af[mi][0] = *(const bf16x8*)(as + row * 128 + ca0);
      af[mi][1] = *(const bf16x8*)(as + row * 128 + ca1);
    }
#pragma unroll
    for (int ni = 0; ni < 4; ++ni) {
      int row = wn * 64 + ni * 16 + r15;
      bf[ni][0] = *(const bf16x8*)(bs + row * 128 + ca0);
      bf[ni][1] = *(const bf16x8*)(bs + row * 128 + ca1);
    }
#pragma unroll
    for (int kk = 0; kk < 2; ++kk)
#pragma unroll
      for (int mi = 0; mi < 4; ++mi)
#pragma unroll
        for (int ni = 0; ni < 4; ++ni)
          acc[mi][ni] = mfma16(af[mi][kk], bf[ni][kk], acc[mi][ni]);
    __syncthreads();
  }

#pragma unroll
  for (int ni = 0; ni < 4; ++ni) {
    int col = blockIdx.y * 128 + wn * 64 + ni * 16 + r15;
    float bv = bias[col];
#pragma unroll
    for (int mi = 0; mi < 4; ++mi) {
      int row0 = blockIdx.x * 128 + wm * 64 + mi * 16 + j * 4;
#pragma unroll
      for (int r = 0; r < 4; ++r) {
        float v = acc[mi][ni][r] + bv;
        if (OUTF32)
          ((float*)Cout)[(size_t)(row0 + r) * N + col] = v;
        else
          ((unsigned short*)Cout)[(size_t)(row0 + r) * N + col] = f2bf(v);
      }
    }
  }
}

// ---------------- fused GQA attention ----------------
// grid (32 qtiles, 32 b*h); 4 waves; TQ=64 (16 q-rows per wave).
// Swapped QK^T: S^T = K*Q^T so lane owns one q-row (col=lane&15) and 4
// consecutive k per reg quad -> float4 attn stores + b64 P-LDS stores.
__global__ __launch_bounds__(256, 2) void k_attn(
    const unsigned short* __restrict__ qp, const unsigned short* __restrict__ kp,
    const unsigned short* __restrict__ vpT, float* __restrict__ attn,
    unsigned short* __restrict__ ctx) {
  __shared__ char lds[57344];
  char* Qs = lds;             // 8KB: 64 rows x 128B, swz c^=row&7
  char* Ks0 = lds + 8192;     // 16KB (pass A dbuf uses 8K..40K; pass B single @8K)
  char* VTs = lds + 24576;    // 16KB: 64 rows x 256B, swz c^=row&15
  char* Ps = lds + 40960;     // 16KB: 64 rows x 256B, swz c^=row&15

  const int lane = threadIdx.x & 63, wid = threadIdx.x >> 6;
  const int r15 = lane & 15, j = lane >> 4;
  const int qt = blockIdx.x, bh = blockIdx.y;
  const int b = bh >> 4, h = bh & 15, kv = h >> 2;
  const int q0 = qt * 64, wq0 = wid * 16;

  const char* qbase = (const char*)qp + (((size_t)(b * S_ + q0)) * D_ + h * HD_) * 2;
  const char* kbase = (const char*)kp + ((size_t)(b * S_) * DKV_ + kv * HD_) * 2;
  const char* vtb = (const char*)vpT + ((size_t)(b * DKV_ + kv * HD_)) * S_ * 2;
  float* attnb = attn + ((size_t)bh * S_ + q0) * S_;

  const int srow8 = lane >> 3;
  const int scol8 = ((lane & 7) ^ srow8) << 4;

  // stage Q (64 rows x 128B = 8 chunks)
#pragma unroll
  for (int i = 0; i < 2; ++i) {
    int chunk = wid * 2 + i;
    gload16(qbase + (size_t)(chunk * 8 + srow8) * (D_ * 2) + scol8, Qs + chunk * 1024);
  }
  auto stageK = [&](int kt, char* dst) {
#pragma unroll
    for (int i = 0; i < 4; ++i) {
      int chunk = i * 4 + wid;
      gload16(kbase + (size_t)(kt * 128 + chunk * 8 + srow8) * (DKV_ * 2) + scol8,
              dst + chunk * 1024);
    }
  };
  auto stageVT = [&](int kt) {
#pragma unroll
    for (int i = 0; i < 4; ++i) {
      int chunk = i * 4 + wid;
      int row = chunk * 4 + j;
      gload16(vtb + (size_t)row * (S_ * 2) + kt * 256 + (((lane & 15) ^ (row & 15)) << 4),
              VTs + chunk * 1024);
    }
  };

  stageK(0, Ks0);
  __syncthreads();

  const int qrow = wq0 + r15;
  const int cq0 = ((0 * 4 + j) ^ (r15 & 7)) << 4;
  const int cq1 = ((1 * 4 + j) ^ (r15 & 7)) << 4;
  const bf16x8 bq0 = *(const bf16x8*)(Qs + qrow * 128 + cq0);
  const bf16x8 bq1 = *(const bf16x8*)(Qs + qrow * 128 + cq1);

  auto qk_tile = [&](const char* ks, f32x4 (&sfr)[8]) {
#pragma unroll
    for (int f = 0; f < 8; ++f) {
      const int krow = f * 16 + r15;
      bf16x8 a0 = *(const bf16x8*)(ks + krow * 128 + cq0);
      bf16x8 a1 = *(const bf16x8*)(ks + krow * 128 + cq1);
      f32x4 z = (f32x4){0.f, 0.f, 0.f, 0.f};
      z = mfma16(a0, bq0, z);
      z = mfma16(a1, bq1, z);
      sfr[f] = z;
    }
  };

  const float cs = 0.125f * 1.44269504088896f;  // SCALE * log2(e)
  float mcur = -1e30f, lsum = 0.f;

  // ---- pass A: flash stats (double-buffered K, 1 barrier/tile) ----
  for (int kt = 0; kt < 16; ++kt) {
    if (kt + 1 < 16) stageK(kt + 1, Ks0 + ((kt + 1) & 1) * 16384);
    const char* ks = Ks0 + (kt & 1) * 16384;
    f32x4 sfr[8];
    qk_tile(ks, sfr);
    float tm = -1e30f;
#pragma unroll
    for (int f = 0; f < 8; ++f)
#pragma unroll
      for (int r = 0; r < 4; ++r) tm = fmaxf(tm, sfr[f][r]);
    tm *= cs;
    tm = fmaxf(tm, __shfl_xor(tm, 16, 64));
    tm = fmaxf(tm, __shfl_xor(tm, 32, 64));
    float mnew = fmaxf(mcur, tm);
    float part = 0.f;
#pragma unroll
    for (int f = 0; f < 8; ++f)
#pragma unroll
      for (int r = 0; r < 4; ++r) part += exp2f(sfr[f][r] * cs - mnew);
    part += __shfl_xor(part, 16, 64);
    part += __shfl_xor(part, 32, 64);
    lsum = lsum * exp2f(mcur - mnew) + part;
    mcur = mnew;
    __syncthreads();
  }
  const float invl = 1.f / lsum;

  // ---- pass B: recompute S, write attn + P, PV accumulate ----
  f32x4 o[4];
#pragma unroll
  for (int nf = 0; nf < 4; ++nf) o[nf] = (f32x4){0.f, 0.f, 0.f, 0.f};

  for (int kt = 0; kt < 16; ++kt) {
    stageK(kt, Ks0);
    stageVT(kt);
    __syncthreads();
    f32x4 sfr[8];
    qk_tile(Ks0, sfr);
#pragma unroll
    for (int f = 0; f < 8; ++f) {
      float4v pv;
#pragma unroll
      for (int r = 0; r < 4; ++r) pv[r] = exp2f(sfr[f][r] * cs - mcur) * invl;
      *(float4v*)(attnb + (size_t)qrow * S_ + kt * 128 + f * 16 + j * 4) = pv;
      s16x4 pb;
#pragma unroll
      for (int r = 0; r < 4; ++r) pb[r] = (short)f2bf(pv[r]);
      int cb = f * 32 + j * 8;
      *(s16x4*)(Ps + qrow * 256 + ((((cb >> 4) ^ r15) << 4) | (cb & 15))) = pb;
    }
    __syncthreads();
#pragma unroll
    for (int ks2 = 0; ks2 < 4; ++ks2) {
      bf16x8 pa = *(const bf16x8*)(Ps + qrow * 256 + (((ks2 * 4 + j) ^ r15) << 4));
#pragma unroll
      for (int nf = 0; nf < 4; ++nf) {
        int vrow = nf * 16 + r15;
        bf16x8 vb = *(const bf16x8*)(VTs + vrow * 256 + (((ks2 * 4 + j) ^ (vrow & 15)) << 4));
        o[nf] = mfma16(pa, vb, o[nf]);
      }
    }
    __syncthreads();
  }

  // ctx write (bf16, scattered b16 — only 8MB total)
#pragma unroll
  for (int nf = 0; nf < 4; ++nf)
#pragma unroll
    for (int r = 0; r < 4; ++r)
      ctx[((size_t)(b * S_ + q0 + wq0 + j * 4 + r)) * D_ + h * HD_ + nf * 16 + r15] =
          f2bf(o[nf][r]);
}

// ---------------- launch ----------------
extern "C" void kernel_launch(void* const* d_in, const int* in_sizes, int n_in,
                              void* d_out, int out_size, void* d_ws, size_t ws_size,
                              hipStream_t stream) {
  (void)in_sizes; (void)n_in; (void)out_size; (void)ws_size;
  const float* q = (const float*)d_in[0];
  const float* Wq = (const float*)d_in[1];
  const float* bq = (const float*)d_in[2];
  const float* Wk = (const float*)d_in[3];
  const float* bk = (const float*)d_in[4];
  const float* Wv = (const float*)d_in[5];
  const float* bv = (const float*)d_in[6];
  const float* Wo = (const float*)d_in[7];
  const float* bo = (const float*)d_in[8];

  char* ws = (char*)d_ws;
  unsigned short* qbf = (unsigned short*)(ws);                       // 8MB
  unsigned short* qpB = (unsigned short*)(ws + (8u << 20));          // 8MB
  unsigned short* kpB = (unsigned short*)(ws + (16u << 20));         // 2MB
  unsigned short* vpB = (unsigned short*)(ws + (18u << 20));         // 2MB
  unsigned short* vpT = (unsigned short*)(ws + (20u << 20));         // 2MB
  unsigned short* ctx = (unsigned short*)(ws + (22u << 20));         // 8MB
  unsigned short* WqT = (unsigned short*)(ws + (30u << 20));         // 2MB
  unsigned short* WkT = (unsigned short*)(ws + (32u << 20));         // 512KB
  unsigned short* WvT = (unsigned short*)(ws + (32u << 20) + (512u << 10));
  unsigned short* WoT = (unsigned short*)(ws + (33u << 20));         // 2MB

  float* out = (float*)d_out;
  float* attn = out + (size_t)B_ * S_ * D_;

  k_cvt<<<4096, 256, 0, stream>>>(q, qbf);
  k_tcvt<<<dim3(32, 32), 256, 0, stream>>>(Wq, WqT, 1024, 1024);
  k_tcvt<<<dim3(8, 32), 256, 0, stream>>>(Wk, WkT, 1024, 256);
  k_tcvt<<<dim3(8, 32), 256, 0, stream>>>(Wv, WvT, 1024, 256);
  k_tcvt<<<dim3(32, 32), 256, 0, stream>>>(Wo, WoT, 1024, 1024);

  k_gemm<false><<<dim3(32, 8), 256, 0, stream>>>(qbf, WqT, bq, qpB, 4096, 1024, 1024);
  k_gemm<false><<<dim3(32, 2), 256, 0, stream>>>(qbf, WkT, bk, kpB, 4096, 256, 1024);
  k_gemm<false><<<dim3(32, 2), 256, 0, stream>>>(qbf, WvT, bv, vpB, 4096, 256, 1024);

  k_tbf<<<dim3(8, 64, 2), 256, 0, stream>>>(vpB, vpT, 2048, 256);

  k_attn<<<dim3(32, 32), 256, 0, stream>>>(qpB, kpB, vpT, attn, ctx);

  k_gemm<true><<<dim3(32, 8), 256, 0, stream>>>(ctx, WoT, bo, out, 4096, 1024, 1024);
}